// Round 1
// baseline (76.929 us; speedup 1.0000x reference)
//
#include <hip/hip_runtime.h>

// CLF-QP batched solver, one thread per state.
// Closed-form fast path: clip(±5) on u=-0.5*nu*a can only bind when
// |a_i| > 2*UB/LAM = 10; when it doesn't bind, g(nu) = b - 0.5*nu*S is
// linear and the reference's bisection+Newton collapses to nu = 2b/S
// exactly. Cold fallback replicates the full bisection+Newton.

#define ADIM 32
static constexpr float LAMP = 1.0f;   // lambda_param
static constexpr float CEXP = 1.0f;   // exp_const
static constexpr float LBND = -5.0f;
static constexpr float UBND = 5.0f;

__global__ __launch_bounds__(256) void clfqp_kernel(
    const float* __restrict__ LfV,
    const float* __restrict__ Lg,
    const float* __restrict__ V,
    float* __restrict__ out,   // [n*ADIM] u, then [n] r
    int n)
{
    int idx = blockIdx.x * blockDim.x + threadIdx.x;
    if (idx >= n) return;

    float b = LfV[idx] + CEXP * V[idx];

    // load a-row (32 floats, 128B contiguous per thread, 8x float4)
    float a[ADIM];
    const float4* a4 = reinterpret_cast<const float4*>(Lg + (size_t)idx * ADIM);
    #pragma unroll
    for (int j = 0; j < ADIM / 4; ++j) {
        float4 v = a4[j];
        a[4*j+0] = v.x; a[4*j+1] = v.y; a[4*j+2] = v.z; a[4*j+3] = v.w;
    }

    // one pass: S = sum a^2, g_lam = g(LAM), amax = max|a|
    float S = 0.0f, glam = b, amax = 0.0f;
    #pragma unroll
    for (int i = 0; i < ADIM; ++i) {
        float ai = a[i];
        S = fmaf(ai, ai, S);
        float t = fminf(fmaxf(-0.5f * LAMP * ai, LBND), UBND);
        glam = fmaf(ai, t, glam);
        amax = fmaxf(amax, fabsf(ai));
    }

    float nu, r;
    if (b <= 0.0f) {
        nu = 0.0f; r = 0.0f;
    } else if (glam > 0.0f) {
        nu = LAMP; r = glam;
    } else {
        r = 0.0f;
        if (0.5f * LAMP * amax > UBND) {
            // cold path: clip can bind inside [0,LAM] -> faithful bisection
            float lo = 0.0f, hi = LAMP;
            #pragma unroll 1
            for (int it = 0; it < 60; ++it) {
                float mid = 0.5f * (lo + hi);
                float g = b;
                #pragma unroll 1
                for (int i = 0; i < ADIM; ++i) {
                    float t = fminf(fmaxf(-0.5f * mid * a[i], LBND), UBND);
                    g = fmaf(a[i], t, g);
                }
                if (g > 0.0f) lo = mid; else hi = mid;
            }
            float nu0 = 0.5f * (lo + hi);
            float g0 = b, dg = 0.0f;
            #pragma unroll 1
            for (int i = 0; i < ADIM; ++i) {
                float u0 = fminf(fmaxf(-0.5f * nu0 * a[i], LBND), UBND);
                g0 = fmaf(a[i], u0, g0);
                if (u0 > LBND && u0 < UBND) dg = fmaf(a[i], a[i], dg);
            }
            dg = -0.5f * dg;
            if (!(dg < 0.0f)) dg = -1.0f;
            nu = nu0 - g0 / dg;
        } else {
            // linear g: Newton step from any nu0 gives exactly 2b/S
            nu = 2.0f * b / S;
        }
    }

    // u = clip(-0.5*nu*a), vectorized store
    float4* u4 = reinterpret_cast<float4*>(out + (size_t)idx * ADIM);
    #pragma unroll
    for (int j = 0; j < ADIM / 4; ++j) {
        float4 v;
        v.x = fminf(fmaxf(-0.5f * nu * a[4*j+0], LBND), UBND);
        v.y = fminf(fmaxf(-0.5f * nu * a[4*j+1], LBND), UBND);
        v.z = fminf(fmaxf(-0.5f * nu * a[4*j+2], LBND), UBND);
        v.w = fminf(fmaxf(-0.5f * nu * a[4*j+3], LBND), UBND);
        u4[j] = v;
    }
    out[(size_t)n * ADIM + idx] = r;
}

extern "C" void kernel_launch(void* const* d_in, const int* in_sizes, int n_in,
                              void* d_out, int out_size, void* d_ws, size_t ws_size,
                              hipStream_t stream) {
    const float* LfV = (const float*)d_in[0];
    const float* Lg  = (const float*)d_in[1];
    const float* V   = (const float*)d_in[2];
    float* out = (float*)d_out;
    int n = in_sizes[0];

    int block = 256;
    int grid = (n + block - 1) / block;
    clfqp_kernel<<<grid, block, 0, stream>>>(LfV, Lg, V, out, n);
}

// Round 2
// 50.256 us; speedup vs baseline: 1.5308x; 1.5308x over previous
//
#include <hip/hip_runtime.h>

// CLF-QP batched solver. One thread per state, but global<->register movement
// of the [256 x 32] f32 L_g_V tile goes through LDS so all global accesses are
// linear/coalesced (1KiB per wave instruction). LDS uses an XOR col-group
// swizzle (cg ^ (row&7)) -- both the coalesced linear phase and the
// per-thread-row phase then hit all 32 banks exactly once per 8-lane group.

#define ADIM 32
#define BLK  256
static constexpr float LAMP = 1.0f;   // lambda_param
static constexpr float CEXP = 1.0f;   // exp_const
static constexpr float LBND = -5.0f;
static constexpr float UBND = 5.0f;

__device__ __forceinline__ float clipu(float x) {
    return fminf(fmaxf(x, LBND), UBND);
}

__global__ __launch_bounds__(BLK) void clfqp_kernel(
    const float* __restrict__ LfV,
    const float* __restrict__ Lg,
    const float* __restrict__ V,
    float* __restrict__ out,   // [n*ADIM] u, then [n] r
    int n)
{
    // [256 rows][8 col-groups of float4], swizzled: cg_phys = cg ^ (row&7).
    // Row stride = 128B == 0 mod (32 banks * 4B), so bank = f(cg_phys) only.
    __shared__ float4 tile[BLK * 8];

    const int t    = threadIdx.x;
    const int base = blockIdx.x * BLK;
    const int idx  = base + t;
    const bool full   = (base + BLK) <= n;
    const bool active = idx < n;

    // ---- phase 1: coalesced global -> LDS (swizzled) ----
    const float4* src = reinterpret_cast<const float4*>(Lg) + (size_t)base * 8;
    if (full) {
        #pragma unroll
        for (int k = 0; k < 8; ++k) {
            int lin4 = k * BLK + t;          // consecutive lanes -> consecutive 16B
            float4 v = src[lin4];
            int r = lin4 >> 3, cg = lin4 & 7;
            tile[r * 8 + (cg ^ (r & 7))] = v;
        }
    } else {
        for (int k = 0; k < 8; ++k) {
            int lin4 = k * BLK + t;
            int r = lin4 >> 3, cg = lin4 & 7;
            if (base + r < n) tile[r * 8 + (cg ^ (r & 7))] = src[lin4];
        }
    }
    __syncthreads();

    // ---- phase 2: per-thread row from LDS, solve QP ----
    float a[ADIM];
    float nu = 0.0f, r_out = 0.0f;
    if (active) {
        #pragma unroll
        for (int j = 0; j < 8; ++j) {
            float4 v = tile[t * 8 + (j ^ (t & 7))];
            a[4*j+0] = v.x; a[4*j+1] = v.y; a[4*j+2] = v.z; a[4*j+3] = v.w;
        }
        float b = LfV[idx] + CEXP * V[idx];

        float S = 0.0f, glam = b, amax = 0.0f;
        #pragma unroll
        for (int i = 0; i < ADIM; ++i) {
            float ai = a[i];
            S = fmaf(ai, ai, S);
            glam = fmaf(ai, clipu(-0.5f * LAMP * ai), glam);
            amax = fmaxf(amax, fabsf(ai));
        }

        if (b <= 0.0f) {
            nu = 0.0f; r_out = 0.0f;
        } else if (glam > 0.0f) {
            nu = LAMP; r_out = glam;
        } else {
            r_out = 0.0f;
            if (0.5f * LAMP * amax > UBND) {
                // cold path: clip can bind inside [0,LAM] -> faithful bisection
                float lo = 0.0f, hi = LAMP;
                #pragma unroll 1
                for (int it = 0; it < 60; ++it) {
                    float mid = 0.5f * (lo + hi);
                    float g = b;
                    #pragma unroll 1
                    for (int i = 0; i < ADIM; ++i)
                        g = fmaf(a[i], clipu(-0.5f * mid * a[i]), g);
                    if (g > 0.0f) lo = mid; else hi = mid;
                }
                float nu0 = 0.5f * (lo + hi);
                float g0 = b, dg = 0.0f;
                #pragma unroll 1
                for (int i = 0; i < ADIM; ++i) {
                    float u0 = clipu(-0.5f * nu0 * a[i]);
                    g0 = fmaf(a[i], u0, g0);
                    if (u0 > LBND && u0 < UBND) dg = fmaf(a[i], a[i], dg);
                }
                dg = -0.5f * dg;
                if (!(dg < 0.0f)) dg = -1.0f;
                nu = nu0 - g0 / dg;
            } else {
                // linear g: Newton step collapses exactly to 2b/S
                nu = 2.0f * b / S;
            }
        }
    }
    __syncthreads();   // tile about to be overwritten

    // ---- phase 3: u into LDS (swizzled, per-thread row) ----
    if (active) {
        #pragma unroll
        for (int j = 0; j < 8; ++j) {
            float4 v;
            v.x = clipu(-0.5f * nu * a[4*j+0]);
            v.y = clipu(-0.5f * nu * a[4*j+1]);
            v.z = clipu(-0.5f * nu * a[4*j+2]);
            v.w = clipu(-0.5f * nu * a[4*j+3]);
            tile[t * 8 + (j ^ (t & 7))] = v;
        }
    }
    __syncthreads();

    // ---- phase 4: coalesced LDS -> global ----
    float4* dst = reinterpret_cast<float4*>(out) + (size_t)base * 8;
    if (full) {
        #pragma unroll
        for (int k = 0; k < 8; ++k) {
            int lin4 = k * BLK + t;
            int r = lin4 >> 3, cg = lin4 & 7;
            dst[lin4] = tile[r * 8 + (cg ^ (r & 7))];
        }
    } else {
        for (int k = 0; k < 8; ++k) {
            int lin4 = k * BLK + t;
            int r = lin4 >> 3, cg = lin4 & 7;
            if (base + r < n) dst[lin4] = tile[r * 8 + (cg ^ (r & 7))];
        }
    }
    if (active) out[(size_t)n * ADIM + idx] = r_out;
}

extern "C" void kernel_launch(void* const* d_in, const int* in_sizes, int n_in,
                              void* d_out, int out_size, void* d_ws, size_t ws_size,
                              hipStream_t stream) {
    const float* LfV = (const float*)d_in[0];
    const float* Lg  = (const float*)d_in[1];
    const float* V   = (const float*)d_in[2];
    float* out = (float*)d_out;
    int n = in_sizes[0];

    int grid = (n + BLK - 1) / BLK;
    clfqp_kernel<<<grid, BLK, 0, stream>>>(LfV, Lg, V, out, n);
}